// Round 4
// baseline (1380.419 us; speedup 1.0000x reference)
//
#include <hip/hip_runtime.h>
#include <stdint.h>

typedef __attribute__((ext_vector_type(8))) short short8;
typedef __attribute__((ext_vector_type(4))) float f32x4;
typedef __attribute__((ext_vector_type(4))) unsigned int u32x4;

struct Ptr6 { const float* p[6]; };

__device__ __forceinline__ float bf2f(unsigned short u){
  union { unsigned int i; float f; } x; x.i = ((unsigned int)u) << 16; return x.f;
}
__device__ __forceinline__ unsigned short f2bf(float f){
  union { float f; unsigned int i; } x; x.f = f;
  unsigned int r = x.i + 0x7fffu + ((x.i >> 16) & 1u);
  return (unsigned short)(r >> 16);
}

// ---------------- hypernet: wa[l][b][k] = y[b]·fc_w[l][k] + fc_b[l][k] ----------------
__global__ void wa_kernel(const float* __restrict__ y, const float* __restrict__ fcw,
                          const float* __restrict__ fcb, float* __restrict__ wa){
  int l = blockIdx.x >> 3, b = blockIdx.x & 7;
  int k = threadIdx.x;
  if (k >= 100) return;
  const float* yr = y + b*512;
  const float* wr = fcw + (l*100 + k)*512;
  float s = 0.f;
  for (int j=0;j<512;j++) s += yr[j]*wr[j];
  wa[(l*8+b)*100 + k] = s + fcb[l*100 + k];
}

// ---------------- all layers: cast WB -> bf16, rows padded, K padded to 128 ----------------
__global__ void wbh_all_kernel(Ptr6 wb, unsigned short* __restrict__ o){
  const int roff1=1536, roff2=3072, roff3=4608, roff4=5376, roff5=5760;
  int idx = blockIdx.x*256 + threadIdx.x;   // 6016*128 total
  int row = idx >> 7, k = idx & 127;
  int l, r;
  if      (row < roff1){ l=0; r=row; }
  else if (row < roff2){ l=1; r=row-roff1; }
  else if (row < roff3){ l=2; r=row-roff2; }
  else if (row < roff4){ l=3; r=row-roff3; }
  else if (row < roff5){ l=4; r=row-roff4; }
  else                 { l=5; r=row-roff5; }
  const int m3[6] = {1536,1536,1536,768,384,192};
  float v = (r < m3[l] && k < 100) ? wb.p[l][r*100 + k] : 0.f;
  o[idx] = f2bf(v);
}

// ---------------- all layers: wach[l][b][i][k] = wa[l][b][k]*WC[l][i][k], K pad 128 -----
__global__ void wach_all_kernel(Ptr6 wc, const float* __restrict__ wa,
                                unsigned short* __restrict__ o){
  const int c1=12288, c2=24576, c3=36864, c4=49152, c5=55296;
  int idx = blockIdx.x*256 + threadIdx.x;   // 58368*128 total
  int row = idx >> 7, k = idx & 127;
  int l, r, n3;
  if      (row < c1){ l=0; r=row;    n3=1536; }
  else if (row < c2){ l=1; r=row-c1; n3=1536; }
  else if (row < c3){ l=2; r=row-c2; n3=1536; }
  else if (row < c4){ l=3; r=row-c3; n3=1536; }
  else if (row < c5){ l=4; r=row-c4; n3=768; }
  else              { l=5; r=row-c5; n3=384; }
  int b = r / n3, i = r % n3;
  float v = (k < 100) ? wa[(l*8+b)*100 + k] * wc.p[l][i*100 + k] : 0.f;
  o[idx] = f2bf(v);
}

// ---------------- weight-gen GEMM: wboi[b][o][i] = WBh[o] · wach[b][i]  (K=128 padded) --
__global__ __launch_bounds__(256) void wgen_kernel(
    const unsigned short* __restrict__ wbh, const unsigned short* __restrict__ wach,
    unsigned short* __restrict__ wboi, int M3, int N3){
  __shared__ unsigned short At[128*136];
  __shared__ unsigned short Bt[128*136];
  const int m0 = blockIdx.x*128, n0 = blockIdx.y*128, b = blockIdx.z;
  const int t = threadIdx.x;
  const unsigned short* As = wbh + (size_t)m0*128;
  const unsigned short* Bs = wach + ((size_t)b*N3 + n0)*128;
  #pragma unroll
  for (int j=0;j<8;j++){
    int c = j*256 + t;
    int row = c >> 4, q = c & 15;
    *(u32x4*)&At[row*136 + q*8] = *(const u32x4*)&As[row*128 + q*8];
    *(u32x4*)&Bt[row*136 + q*8] = *(const u32x4*)&Bs[row*128 + q*8];
  }
  __syncthreads();
  const int wv = t >> 6, lane = t & 63;
  const int wm = (wv >> 1)*64, wn = (wv & 1)*64;
  const int lr = lane & 15, lkg = lane >> 4, lk8 = lkg*8;
  f32x4 acc[4][4];
  #pragma unroll
  for (int i=0;i<4;i++) for (int j=0;j<4;j++) acc[i][j] = (f32x4){0,0,0,0};
  #pragma unroll
  for (int kc=0;kc<4;kc++){
    short8 a[4], bv[4];
    #pragma unroll
    for (int mi=0;mi<4;mi++) a[mi] = *(const short8*)&At[(wm+mi*16+lr)*136 + kc*32 + lk8];
    #pragma unroll
    for (int ni=0;ni<4;ni++) bv[ni] = *(const short8*)&Bt[(wn+ni*16+lr)*136 + kc*32 + lk8];
    #pragma unroll
    for (int mi=0;mi<4;mi++)
      #pragma unroll
      for (int ni=0;ni<4;ni++)
        acc[mi][ni] = __builtin_amdgcn_mfma_f32_16x16x32_bf16(a[mi], bv[ni], acc[mi][ni], 0,0,0);
  }
  #pragma unroll
  for (int mi=0;mi<4;mi++)
    #pragma unroll
    for (int ni=0;ni<4;ni++)
      #pragma unroll
      for (int r=0;r<4;r++){
        int o = m0 + wm + mi*16 + lkg*4 + r;
        int i = n0 + wn + ni*16 + lr;
        if (o < M3) wboi[((size_t)b*M3 + o)*N3 + i] = f2bf(acc[mi][ni][r]);
      }
}

// ---------------- weight transpose (16B vector stores):
// W2[b][tap][co][ci] = wboi[b][3co + t/(3cin)][t mod 3cin], t = ci*9+tap ----------------
__global__ void wtr_kernel(const unsigned short* __restrict__ wboi, unsigned short* __restrict__ W2,
                           int CIN, int COUT){
  __shared__ unsigned short buf[9*512];
  const int bid = blockIdx.x;
  const int co = bid % COUT, b = bid / COUT;
  const int t = threadIdx.x;
  const int n = 9*CIN;
  const unsigned short* src = wboi + ((size_t)b*3*COUT + 3*co)*(size_t)(3*CIN);
  for (int i = t*8; i < n; i += 2048) *(u32x4*)&buf[i] = *(const u32x4*)&src[i];
  __syncthreads();
  const int nch = n >> 3;       // 16B chunks of output
  const int cpr = CIN >> 3;     // chunks per tap-row
  for (int idx = t; idx < nch; idx += 256){
    int tap = idx / cpr, cig = idx - tap*cpr;
    short8 v;
    #pragma unroll
    for (int j=0;j<8;j++) v[j] = (short)buf[(cig*8+j)*9 + tap];
    *(short8*)&W2[(((size_t)(b*9 + tap)*COUT) + co)*CIN + cig*8] = v;
  }
}

// ---------------- cast x (NCHW f32) -> padded NHWC bf16 [8][68][68][512] ----------------
__global__ void castx_kernel(const float* __restrict__ x, unsigned short* __restrict__ act){
  __shared__ float tile[64][65];
  int bid = blockIdx.x;
  int ct = bid & 7; int hp = (bid >> 3) % 68; int b = bid / 544;
  int c0 = ct * 64;
  int t = threadIdx.x;
  unsigned short* orow = act + ((size_t)(b*68 + hp)*68)*512;
  if (hp < 2 || hp >= 66){
    for (int idx = t; idx < 68*64; idx += 256){
      int wp = idx >> 6, c = idx & 63;
      orow[wp*512 + c0 + c] = 0;
    }
    return;
  }
  int h = hp - 2;
  for (int idx = t; idx < 64*64; idx += 256){
    int r = idx >> 6, w = idx & 63;
    tile[r][w] = x[((size_t)(b*512 + c0 + r)*64 + h)*64 + w];
  }
  __syncthreads();
  for (int idx = t; idx < 68*64; idx += 256){
    int wp = idx >> 6, c = idx & 63;
    float v = (wp < 2 || wp >= 66) ? 0.f : tile[c][wp-2];
    orow[wp*512 + c0 + c] = f2bf(v);
  }
}

// ---------------- conv: implicit GEMM + fused BN-stat epilogue ----------------
template<int CIN, int COUT>
__global__ __launch_bounds__(256, 2) void conv_kernel(
    const unsigned short* __restrict__ act, const unsigned short* __restrict__ W2,
    float* __restrict__ cbuf, float* __restrict__ bnacc){
  __shared__ unsigned short Al[9*64*40];   // [tap][co][ci(32, pad40)]
  __shared__ unsigned short Pl[20*20*40];  // [ph][pw][ci(32, pad40)]
  const int co0 = blockIdx.x * 64;
  const int h0 = (blockIdx.y >> 2) * 16;
  const int w0 = (blockIdx.y & 3) * 16;
  const int b = blockIdx.z;
  const int t = threadIdx.x;
  const int wv = t >> 6, lane = t & 63;
  const int lr = lane & 15, lkg = lane >> 4, lk8 = lkg*8;

  const unsigned short* actb = act + (size_t)b*68*68*CIN;
  const unsigned short* wb = W2 + (size_t)b*9*COUT*CIN;

  f32x4 acc[4][4];
  #pragma unroll
  for (int i=0;i<4;i++) for (int j=0;j<4;j++) acc[i][j] = (f32x4){0,0,0,0};

  for (int cs = 0; cs < CIN/32; ++cs){
    const int cb = cs*32;
    #pragma unroll
    for (int j=0;j<9;j++){                    // A: 9*64*32 = 2304 16B-chunks
      int c = j*256 + t;
      int tap = c >> 8, rem = c & 255;
      int co = rem >> 2, q = rem & 3;
      u32x4 v = *(const u32x4*)&wb[((size_t)(tap*COUT + co0 + co))*CIN + cb + q*8];
      *(u32x4*)&Al[(tap*64 + co)*40 + q*8] = v;
    }
    #pragma unroll
    for (int j=0;j<7;j++){                    // patch: 20*20*32 = 1600 16B-chunks
      int c = j*256 + t;
      if (c < 1600){
        int ph = c/80, rem = c%80, pw = rem>>2, q = rem&3;
        u32x4 v = *(const u32x4*)&actb[(size_t)((h0+ph)*68 + (w0+pw))*CIN + cb + q*8];
        *(u32x4*)&Pl[(ph*20+pw)*40 + q*8] = v;
      }
    }
    __syncthreads();
    #pragma unroll
    for (int kh=0;kh<3;kh++){
      #pragma unroll
      for (int kw=0;kw<3;kw++){
        const int tap = kh*3 + kw;
        short8 a[4], bv[4];
        #pragma unroll
        for (int mi=0;mi<4;mi++)
          a[mi] = *(const short8*)&Al[(tap*64 + mi*16 + lr)*40 + lk8];
        #pragma unroll
        for (int ni=0;ni<4;ni++){
          int pr = wv*4 + ni + 2*kh;
          int pc = lr + 2*kw;
          bv[ni] = *(const short8*)&Pl[(pr*20 + pc)*40 + lk8];
        }
        #pragma unroll
        for (int mi=0;mi<4;mi++)
          #pragma unroll
          for (int ni=0;ni<4;ni++)
            acc[mi][ni] = __builtin_amdgcn_mfma_f32_16x16x32_bf16(a[mi], bv[ni], acc[mi][ni], 0,0,0);
      }
    }
    __syncthreads();
  }
  float* ob = cbuf + (size_t)b*64*64*COUT;
  #pragma unroll
  for (int mi=0;mi<4;mi++){
    int co = co0 + mi*16 + lkg*4;
    #pragma unroll
    for (int ni=0;ni<4;ni++){
      int hh = h0 + wv*4 + ni;
      int ww = w0 + lr;
      *(f32x4*)&ob[(size_t)(hh*64 + ww)*COUT + co] = acc[mi][ni];
    }
  }
  // fused BN statistics: per-thread partial over its 4 px-rows, butterfly over lr lanes
  float ps[4][4], pq[4][4];
  #pragma unroll
  for (int mi=0;mi<4;mi++)
    #pragma unroll
    for (int r=0;r<4;r++){ ps[mi][r]=0.f; pq[mi][r]=0.f; }
  #pragma unroll
  for (int mi=0;mi<4;mi++)
    #pragma unroll
    for (int ni=0;ni<4;ni++)
      #pragma unroll
      for (int r=0;r<4;r++){
        float v = acc[mi][ni][r];
        ps[mi][r] += v; pq[mi][r] += v*v;
      }
  #pragma unroll
  for (int m=1;m<16;m<<=1)
    #pragma unroll
    for (int mi=0;mi<4;mi++)
      #pragma unroll
      for (int r=0;r<4;r++){
        ps[mi][r] += __shfl_xor(ps[mi][r], m);
        pq[mi][r] += __shfl_xor(pq[mi][r], m);
      }
  if (lr == 0){
    #pragma unroll
    for (int mi=0;mi<4;mi++)
      #pragma unroll
      for (int r=0;r<4;r++){
        int co = co0 + mi*16 + lkg*4 + r;
        atomicAdd(&bnacc[co], ps[mi][r]);
        atomicAdd(&bnacc[512 + co], pq[mi][r]);
      }
  }
}

// ---------------- BN apply + ReLU + bf16 cast into padded NHWC (computes mean/rsq) ------
__global__ void bnapply_kernel(const float* __restrict__ cbuf, const float* __restrict__ bnacc,
                               unsigned short* __restrict__ actout, int lc){
  const int C = 1 << lc;
  const int bid = blockIdx.x;
  const int hp = bid % 68, b = bid / 68;
  const int t = threadIdx.x;
  unsigned short* orow = actout + (((size_t)(b*68 + hp))*68 << lc);
  const bool hb = (hp < 2) || (hp >= 66);
  const int n = 68 << lc;
  const float inv_n = 1.f/32768.f;
  for (int idx = t; idx < n; idx += 256){
    int wp = idx >> lc, c = idx & (C-1);
    float v = 0.f;
    if (!hb && wp >= 2 && wp < 66){
      float s = bnacc[c], qq = bnacc[512 + c];
      float mean = s*inv_n;
      float var = qq*inv_n - mean*mean;
      float rs = rsqrtf(var + 1e-5f);
      float xx = cbuf[((((size_t)b*64 + (hp-2))*64 + (wp-2)) << lc) + c];
      float z = (xx - mean) * rs;
      v = z > 0.f ? z : 0.f;
    }
    orow[idx] = f2bf(v);
  }
}

// ---------------- fused 1x1 conv (64->1) + 8x nearest upsample ----------------
__global__ void convup_kernel(const unsigned short* __restrict__ act, const float* __restrict__ ow,
                              const float* __restrict__ ob, float* __restrict__ out){
  int idx = blockIdx.x*256 + threadIdx.x;   // 8*4096
  int b = idx >> 12, p = idx & 4095;
  int h = p >> 6, w = p & 63;
  const unsigned short* ar = act + (((size_t)(b*68 + h+2))*68 + (w+2))*64;
  float s = 0.f;
  #pragma unroll
  for (int c=0;c<64;c++) s += bf2f(ar[c]) * ow[c];
  s += ob[0];
  f32x4 v = {s,s,s,s};
  float* o = out + (((size_t)b*512 + h*8)*512) + w*8;
  #pragma unroll
  for (int rr=0;rr<8;rr++){
    *(f32x4*)(o + (size_t)rr*512) = v;
    *(f32x4*)(o + (size_t)rr*512 + 4) = v;
  }
}

extern "C" void kernel_launch(void* const* d_in, const int* in_sizes, int n_in,
                              void* d_out, int out_size, void* d_ws, size_t ws_size,
                              hipStream_t stream){
  const float* x   = (const float*)d_in[0];
  const float* y   = (const float*)d_in[1];
  const float* fcw = (const float*)d_in[2];
  const float* fcb = (const float*)d_in[3];
  Ptr6 wbp, wcp;
  // setup_inputs dict order interleaves wb/wc; reference signature groups them.
  // Disambiguate via in_sizes[10]: dict order -> wb3 (768*100=76800); sig order -> wc0 (153600).
  bool dictOrder = (in_sizes[10] == 76800);
  for (int i=0;i<6;i++){
    if (dictOrder){ wbp.p[i] = (const float*)d_in[4+2*i]; wcp.p[i] = (const float*)d_in[5+2*i]; }
    else          { wbp.p[i] = (const float*)d_in[4+i];   wcp.p[i] = (const float*)d_in[10+i]; }
  }
  const float* ow  = (const float*)d_in[16];
  const float* obp = (const float*)d_in[17];
  float* out = (float*)d_out;

  static const int CIN[6]  = {512,512,512,512,256,128};
  static const int COUT[6] = {512,512,512,256,128,64};
  static const int MPAD[6] = {1536,1536,1536,768,384,256};
  static const int LC[6]   = {9,9,9,8,7,6};

  char* ws = (char*)d_ws; size_t off = 0;
  auto alloc = [&](size_t bytes)->void*{ void* p = ws + off; off += (bytes + 255) & ~(size_t)255; return p; };
  unsigned short* actA = (unsigned short*)alloc((size_t)8*68*68*512*2);
  unsigned short* actB = (unsigned short*)alloc((size_t)8*68*68*512*2);
  float* cbuf = (float*)alloc((size_t)8*64*64*512*4);      // 64MB; also aliases wboi (37.75MB)
  unsigned short* wboi = (unsigned short*)cbuf;            // dead before conv writes cbuf
  unsigned short* W2 = (unsigned short*)alloc((size_t)8*9*512*512*2);
  float* wa = (float*)alloc(6*8*100*4);
  unsigned short* wbh = (unsigned short*)alloc((size_t)6016*128*2);
  unsigned short* wach = (unsigned short*)alloc((size_t)58368*128*2);
  float* bnacc = (float*)alloc(6*1024*4);                  // [layer][{sum[512],sumsq[512]}]
  float* out64 = (float*)alloc(8*4096*4);
  (void)out64;

  wa_kernel<<<48, 128, 0, stream>>>(y, fcw, fcb, wa);
  wbh_all_kernel<<<6016*128/256, 256, 0, stream>>>(wbp, wbh);
  wach_all_kernel<<<58368*128/256, 256, 0, stream>>>(wcp, wa, wach);
  hipMemsetAsync(bnacc, 0, 6*1024*sizeof(float), stream);
  castx_kernel<<<8*68*8, 256, 0, stream>>>(x, actA);

  static const int MOFF[6] = {0,1536,3072,4608,5376,5760};
  static const int COFF[6] = {0,12288,24576,36864,49152,55296};

  unsigned short* ain = actA; unsigned short* aout = actB;
  for (int l=0;l<6;l++){
    int M3 = 3*COUT[l], N3 = 3*CIN[l];
    const unsigned short* wbh_l = wbh + (size_t)MOFF[l]*128;
    const unsigned short* wach_l = wach + (size_t)COFF[l]*128;
    float* bnacc_l = bnacc + l*1024;
    wgen_kernel<<<dim3(MPAD[l]/128, N3/128, 8), 256, 0, stream>>>(wbh_l, wach_l, wboi, M3, N3);
    wtr_kernel<<<8*COUT[l], 256, 0, stream>>>(wboi, W2, CIN[l], COUT[l]);
    switch(l){
      case 0: case 1: case 2:
        conv_kernel<512,512><<<dim3(8,16,8),256,0,stream>>>(ain, W2, cbuf, bnacc_l); break;
      case 3:
        conv_kernel<512,256><<<dim3(4,16,8),256,0,stream>>>(ain, W2, cbuf, bnacc_l); break;
      case 4:
        conv_kernel<256,128><<<dim3(2,16,8),256,0,stream>>>(ain, W2, cbuf, bnacc_l); break;
      case 5:
        conv_kernel<128,64><<<dim3(1,16,8),256,0,stream>>>(ain, W2, cbuf, bnacc_l); break;
    }
    bnapply_kernel<<<8*68, 256, 0, stream>>>(cbuf, bnacc_l, aout, LC[l]);
    unsigned short* tmp = ain; ain = aout; aout = tmp;
  }
  convup_kernel<<<(8*4096)/256, 256, 0, stream>>>(ain, ow, obp, out);
}

// Round 8
// 1255.239 us; speedup vs baseline: 1.0997x; 1.0997x over previous
//
#include <hip/hip_runtime.h>
#include <stdint.h>

typedef __attribute__((ext_vector_type(8))) short short8;
typedef __attribute__((ext_vector_type(4))) float f32x4;
typedef __attribute__((ext_vector_type(4))) unsigned int u32x4;

struct Ptr6 { const float* p[6]; };

struct LTab {
  const unsigned short* wbh; const unsigned short* wach;
  unsigned short* wboi; unsigned short* w2;
  int cumg[7]; int cumt[7];
  int mblk[6]; int nblk[6]; int M3[6]; int N3[6]; int CINt[6]; int COUTt[6];
  long moff[6]; long coff[6]; long woff[6];
};

__device__ __forceinline__ float bf2f(unsigned short u){
  union { unsigned int i; float f; } x; x.i = ((unsigned int)u) << 16; return x.f;
}
__device__ __forceinline__ unsigned short f2bf(float f){
  union { float f; unsigned int i; } x; x.f = f;
  unsigned int r = x.i + 0x7fffu + ((x.i >> 16) & 1u);
  return (unsigned short)(r >> 16);
}

// ---------------- hypernet: wa[l][b][k] = y[b]·fc_w[l][k] + fc_b[l][k] ----------------
__global__ void wa_kernel(const float* __restrict__ y, const float* __restrict__ fcw,
                          const float* __restrict__ fcb, float* __restrict__ wa){
  int l = blockIdx.x >> 3, b = blockIdx.x & 7;
  int k = threadIdx.x;
  if (k >= 100) return;
  const float* yr = y + b*512;
  const float* wr = fcw + (l*100 + k)*512;
  float s = 0.f;
  for (int j=0;j<512;j++) s += yr[j]*wr[j];
  wa[(l*8+b)*100 + k] = s + fcb[l*100 + k];
}

// ---------------- all layers: cast WB -> bf16, rows padded, K padded to 128 -------------
__global__ void wbh_all_kernel(Ptr6 wb, unsigned short* __restrict__ o){
  const int roff1=1536, roff2=3072, roff3=4608, roff4=5376, roff5=5760;
  int idx = blockIdx.x*256 + threadIdx.x;   // 6016*128 total
  int row = idx >> 7, k = idx & 127;
  int l, r;
  if      (row < roff1){ l=0; r=row; }
  else if (row < roff2){ l=1; r=row-roff1; }
  else if (row < roff3){ l=2; r=row-roff2; }
  else if (row < roff4){ l=3; r=row-roff3; }
  else if (row < roff5){ l=4; r=row-roff4; }
  else                 { l=5; r=row-roff5; }
  const int m3[6] = {1536,1536,1536,768,384,192};
  float v = (r < m3[l] && k < 100) ? wb.p[l][r*100 + k] : 0.f;
  o[idx] = f2bf(v);
}

// ---------------- all layers: wach[l][b][i][k] = wa[l][b][k]*WC[l][i][k], K pad 128 -----
__global__ void wach_all_kernel(Ptr6 wc, const float* __restrict__ wa,
                                unsigned short* __restrict__ o){
  const int c1=12288, c2=24576, c3=36864, c4=49152, c5=55296;
  int idx = blockIdx.x*256 + threadIdx.x;   // 58368*128 total
  int row = idx >> 7, k = idx & 127;
  int l, r, n3;
  if      (row < c1){ l=0; r=row;    n3=1536; }
  else if (row < c2){ l=1; r=row-c1; n3=1536; }
  else if (row < c3){ l=2; r=row-c2; n3=1536; }
  else if (row < c4){ l=3; r=row-c3; n3=1536; }
  else if (row < c5){ l=4; r=row-c4; n3=768; }
  else              { l=5; r=row-c5; n3=384; }
  int b = r / n3, i = r % n3;
  float v = (k < 100) ? wa[(l*8+b)*100 + k] * wc.p[l][i*100 + k] : 0.f;
  o[idx] = f2bf(v);
}

// ---------------- weight-gen GEMM body: wboi[b][o][i] = WBh[o]·wach[b][i] (K=128) -------
__device__ __forceinline__ void wgen_body(
    const unsigned short* __restrict__ wbh, const unsigned short* __restrict__ wach,
    unsigned short* __restrict__ wboi, int M3, int N3, int m0, int n0, int b,
    unsigned short* At, unsigned short* Bt){
  const int t = threadIdx.x;
  const unsigned short* As = wbh + (size_t)m0*128;
  const unsigned short* Bs = wach + ((size_t)b*N3 + n0)*128;
  #pragma unroll
  for (int j=0;j<8;j++){
    int c = j*256 + t;
    int row = c >> 4, q = c & 15;
    *(u32x4*)&At[row*136 + q*8] = *(const u32x4*)&As[row*128 + q*8];
    *(u32x4*)&Bt[row*136 + q*8] = *(const u32x4*)&Bs[row*128 + q*8];
  }
  __syncthreads();
  const int wv = t >> 6, lane = t & 63;
  const int wm = (wv >> 1)*64, wn = (wv & 1)*64;
  const int lr = lane & 15, lkg = lane >> 4, lk8 = lkg*8;
  f32x4 acc[4][4];
  #pragma unroll
  for (int i=0;i<4;i++) for (int j=0;j<4;j++) acc[i][j] = (f32x4){0,0,0,0};
  #pragma unroll
  for (int kc=0;kc<4;kc++){
    short8 a[4], bv[4];
    #pragma unroll
    for (int mi=0;mi<4;mi++) a[mi] = *(const short8*)&At[(wm+mi*16+lr)*136 + kc*32 + lk8];
    #pragma unroll
    for (int ni=0;ni<4;ni++) bv[ni] = *(const short8*)&Bt[(wn+ni*16+lr)*136 + kc*32 + lk8];
    #pragma unroll
    for (int mi=0;mi<4;mi++)
      #pragma unroll
      for (int ni=0;ni<4;ni++)
        acc[mi][ni] = __builtin_amdgcn_mfma_f32_16x16x32_bf16(a[mi], bv[ni], acc[mi][ni], 0,0,0);
  }
  #pragma unroll
  for (int mi=0;mi<4;mi++)
    #pragma unroll
    for (int ni=0;ni<4;ni++)
      #pragma unroll
      for (int r=0;r<4;r++){
        int o = m0 + wm + mi*16 + lkg*4 + r;
        int i = n0 + wn + ni*16 + lr;
        if (o < M3) wboi[((size_t)b*M3 + o)*N3 + i] = f2bf(acc[mi][ni][r]);
      }
}

__global__ __launch_bounds__(256) void wgen_all_kernel(LTab tab){
  __shared__ unsigned short At[128*136];
  __shared__ unsigned short Bt[128*136];
  int bid = blockIdx.x;
  int l = 0;
  #pragma unroll
  for (int i=1;i<6;i++) if (bid >= tab.cumg[i]) l = i;
  int rem = bid - tab.cumg[l];
  int mb = rem % tab.mblk[l];
  int r2 = rem / tab.mblk[l];
  int nb = r2 % tab.nblk[l];
  int b  = r2 / tab.nblk[l];
  wgen_body(tab.wbh + tab.moff[l]*128, tab.wach + tab.coff[l]*128,
            tab.wboi + tab.woff[l], tab.M3[l], tab.N3[l], mb*128, nb*128, b, At, Bt);
}

__global__ __launch_bounds__(256) void wgen_kernel(
    const unsigned short* __restrict__ wbh, const unsigned short* __restrict__ wach,
    unsigned short* __restrict__ wboi, int M3, int N3){
  __shared__ unsigned short At[128*136];
  __shared__ unsigned short Bt[128*136];
  wgen_body(wbh, wach, wboi, M3, N3, blockIdx.x*128, blockIdx.y*128, blockIdx.z, At, Bt);
}

// ---------------- weight transpose body: W2[b][tap][co][ci] <- wboi, 16B stores ---------
__device__ __forceinline__ void wtr_body(
    const unsigned short* __restrict__ wboi, unsigned short* __restrict__ W2,
    int CIN, int COUT, int co, int b, unsigned short* buf){
  const int t = threadIdx.x;
  const int n = 9*CIN;
  const unsigned short* src = wboi + ((size_t)b*3*COUT + 3*co)*(size_t)(3*CIN);
  for (int i = t*8; i < n; i += 2048) *(u32x4*)&buf[i] = *(const u32x4*)&src[i];
  __syncthreads();
  const int nch = n >> 3;
  const int cpr = CIN >> 3;
  for (int idx = t; idx < nch; idx += 256){
    int tap = idx / cpr, cig = idx - tap*cpr;
    short8 v;
    #pragma unroll
    for (int j=0;j<8;j++) v[j] = (short)buf[(cig*8+j)*9 + tap];
    *(short8*)&W2[(((size_t)(b*9 + tap)*COUT) + co)*CIN + cig*8] = v;
  }
}

__global__ void wtr_all_kernel(LTab tab){
  __shared__ unsigned short buf[9*512];
  int bid = blockIdx.x;
  int l = 0;
  #pragma unroll
  for (int i=1;i<6;i++) if (bid >= tab.cumt[i]) l = i;
  int rem = bid - tab.cumt[l];
  int co = rem % tab.COUTt[l];
  int b  = rem / tab.COUTt[l];
  wtr_body(tab.wboi + tab.woff[l], tab.w2 + tab.woff[l], tab.CINt[l], tab.COUTt[l], co, b, buf);
}

__global__ void wtr_kernel(const unsigned short* __restrict__ wboi, unsigned short* __restrict__ W2,
                           int CIN, int COUT){
  __shared__ unsigned short buf[9*512];
  wtr_body(wboi, W2, CIN, COUT, blockIdx.x % COUT, blockIdx.x / COUT, buf);
}

// ---------------- cast x (NCHW f32) -> padded NHWC bf16 [8][68][68][512] ----------------
__global__ void castx_kernel(const float* __restrict__ x, unsigned short* __restrict__ act){
  __shared__ float tile[64][65];
  int bid = blockIdx.x;
  int ct = bid & 7; int hp = (bid >> 3) % 68; int b = bid / 544;
  int c0 = ct * 64;
  int t = threadIdx.x;
  unsigned short* orow = act + ((size_t)(b*68 + hp)*68)*512;
  if (hp < 2 || hp >= 66){
    for (int idx = t; idx < 68*64; idx += 256){
      int wp = idx >> 6, c = idx & 63;
      orow[wp*512 + c0 + c] = 0;
    }
    return;
  }
  int h = hp - 2;
  for (int idx = t; idx < 64*64; idx += 256){
    int r = idx >> 6, w = idx & 63;
    tile[r][w] = x[((size_t)(b*512 + c0 + r)*64 + h)*64 + w];
  }
  __syncthreads();
  for (int idx = t; idx < 68*64; idx += 256){
    int wp = idx >> 6, c = idx & 63;
    float v = (wp < 2 || wp >= 66) ? 0.f : tile[c][wp-2];
    orow[wp*512 + c0 + c] = f2bf(v);
  }
}

// ---------------- conv: implicit GEMM, swizzled LDS (conflict-free), partial BN stats ---
// Al chunks [tap][q(4)][co(64)] slot co^q ; Pl chunks [ph][pw][q(4)] slot q^((pw>>1)&3)
template<int CIN, int COUT>
__global__ __launch_bounds__(256, 2) void conv_kernel(
    const unsigned short* __restrict__ act, const unsigned short* __restrict__ W2,
    float* __restrict__ cbuf, float* __restrict__ partial){
  __shared__ unsigned short Al[9*256*8];    // 36864 B
  __shared__ unsigned short Pl[20*20*4*8];  // 25600 B
  const int co0 = blockIdx.x * 64;
  const int h0 = (blockIdx.y >> 2) * 16;
  const int w0 = (blockIdx.y & 3) * 16;
  const int b = blockIdx.z;
  const int t = threadIdx.x;
  const int wv = t >> 6, lane = t & 63;
  const int lr = lane & 15, lkg = lane >> 4;

  const unsigned short* actb = act + (size_t)b*68*68*CIN;
  const unsigned short* wb = W2 + (size_t)b*9*COUT*CIN;

  f32x4 acc[4][4];
  #pragma unroll
  for (int i=0;i<4;i++) for (int j=0;j<4;j++) acc[i][j] = (f32x4){0,0,0,0};

  for (int cs = 0; cs < CIN/32; ++cs){
    const int cb = cs*32;
    #pragma unroll
    for (int j=0;j<9;j++){                    // A: 2304 chunks
      int c = j*256 + t;
      int tap = c >> 8, rem = c & 255;
      int co = rem >> 2, q = rem & 3;
      u32x4 v = *(const u32x4*)&wb[((size_t)(tap*COUT + co0 + co))*CIN + cb + q*8];
      *(u32x4*)&Al[(tap*256 + q*64 + (co^q))*8] = v;
    }
    #pragma unroll
    for (int j=0;j<7;j++){                    // patch: 1600 chunks
      int c = j*256 + t;
      if (c < 1600){
        int ph = c/80, rem = c%80, pw = rem>>2, q = rem&3;
        u32x4 v = *(const u32x4*)&actb[(size_t)((h0+ph)*68 + (w0+pw))*CIN + cb + q*8];
        *(u32x4*)&Pl[((ph*20+pw)*4 + (q ^ ((pw>>1)&3)))*8] = v;
      }
    }
    __syncthreads();
    #pragma unroll
    for (int kh=0;kh<3;kh++){
      #pragma unroll
      for (int kw=0;kw<3;kw++){
        const int tap = kh*3 + kw;
        short8 a[4], bv[4];
        #pragma unroll
        for (int mi=0;mi<4;mi++)
          a[mi] = *(const short8*)&Al[(tap*256 + lkg*64 + ((mi*16+lr)^lkg))*8];
        #pragma unroll
        for (int ni=0;ni<4;ni++){
          int pr = wv*4 + ni + 2*kh;
          int pc = lr + 2*kw;
          bv[ni] = *(const short8*)&Pl[((pr*20+pc)*4 + (lkg ^ ((pc>>1)&3)))*8];
        }
        #pragma unroll
        for (int mi=0;mi<4;mi++)
          #pragma unroll
          for (int ni=0;ni<4;ni++)
            acc[mi][ni] = __builtin_amdgcn_mfma_f32_16x16x32_bf16(a[mi], bv[ni], acc[mi][ni], 0,0,0);
      }
    }
    __syncthreads();
  }
  float* ob = cbuf + (size_t)b*64*64*COUT;
  #pragma unroll
  for (int mi=0;mi<4;mi++){
    int co = co0 + mi*16 + lkg*4;
    #pragma unroll
    for (int ni=0;ni<4;ni++){
      int hh = h0 + wv*4 + ni;
      int ww = w0 + lr;
      *(f32x4*)&ob[(size_t)(hh*64 + ww)*COUT + co] = acc[mi][ni];
    }
  }
  // BN partial stats: butterfly over the 16 lr lanes, deterministic per-(tile,wave) store
  float ps[4][4], pq[4][4];
  #pragma unroll
  for (int mi=0;mi<4;mi++)
    #pragma unroll
    for (int r=0;r<4;r++){ ps[mi][r]=0.f; pq[mi][r]=0.f; }
  #pragma unroll
  for (int mi=0;mi<4;mi++)
    #pragma unroll
    for (int ni=0;ni<4;ni++)
      #pragma unroll
      for (int r=0;r<4;r++){
        float v = acc[mi][ni][r];
        ps[mi][r] += v; pq[mi][r] += v*v;
      }
  #pragma unroll
  for (int m=1;m<16;m<<=1)
    #pragma unroll
    for (int mi=0;mi<4;mi++)
      #pragma unroll
      for (int r=0;r<4;r++){
        ps[mi][r] += __shfl_xor(ps[mi][r], m);
        pq[mi][r] += __shfl_xor(pq[mi][r], m);
      }
  if (lr == 0){
    // 128 spatial tiles x 4 waves = 512 deterministic slots per channel
    const int tile = (blockIdx.y*8 + blockIdx.z)*4 + wv;
    #pragma unroll
    for (int mi=0;mi<4;mi++)
      #pragma unroll
      for (int r=0;r<4;r++){
        int co = co0 + mi*16 + lkg*4 + r;
        ((float2*)partial)[co*512 + tile] = make_float2(ps[mi][r], pq[mi][r]);
      }
  }
}

// ---------------- reduce partials -> mean / rsqrt ----------------
__global__ void bnfin_kernel(const float* __restrict__ partial, float* __restrict__ bnmr, int C){
  int c = blockIdx.x*256 + threadIdx.x;
  if (c >= C) return;
  float s=0.f, q=0.f;
  for (int tl=0; tl<512; ++tl){
    float2 v = ((const float2*)partial)[c*512 + tl];
    s += v.x; q += v.y;
  }
  const float inv_n = 1.f/32768.f;
  float mean = s*inv_n;
  float var = q*inv_n - mean*mean;
  bnmr[c] = mean;
  bnmr[512 + c] = rsqrtf(var + 1e-5f);
}

// ---------------- BN apply + ReLU + bf16 cast into padded NHWC (writes border zeros) ----
__global__ void bnapply_kernel(const float* __restrict__ cbuf, const float* __restrict__ bnmr,
                               unsigned short* __restrict__ actout, int lc){
  const int C = 1 << lc;
  const int bid = blockIdx.x;
  const int hp = bid % 68, b = bid / 68;
  const int t = threadIdx.x;
  unsigned short* orow = actout + (((size_t)(b*68 + hp))*68 << lc);
  const bool hb = (hp < 2) || (hp >= 66);
  const int n = 68 << lc;
  for (int idx = t; idx < n; idx += 256){
    int wp = idx >> lc, c = idx & (C-1);
    float v = 0.f;
    if (!hb && wp >= 2 && wp < 66){
      float xx = cbuf[((((size_t)b*64 + (hp-2))*64 + (wp-2)) << lc) + c];
      float z = (xx - bnmr[c]) * bnmr[512 + c];
      v = z > 0.f ? z : 0.f;
    }
    orow[idx] = f2bf(v);
  }
}

// ---------------- fused 1x1 conv (64->1) + 8x nearest upsample ----------------
__global__ void convup_kernel(const unsigned short* __restrict__ act, const float* __restrict__ ow,
                              const float* __restrict__ ob, float* __restrict__ out){
  int idx = blockIdx.x*256 + threadIdx.x;   // 8*4096
  int b = idx >> 12, p = idx & 4095;
  int h = p >> 6, w = p & 63;
  const unsigned short* ar = act + (((size_t)(b*68 + h+2))*68 + (w+2))*64;
  float s = 0.f;
  #pragma unroll
  for (int c=0;c<64;c++) s += bf2f(ar[c]) * ow[c];
  s += ob[0];
  f32x4 v = {s,s,s,s};
  float* o = out + (((size_t)b*512 + h*8)*512) + w*8;
  #pragma unroll
  for (int rr=0;rr<8;rr++){
    *(f32x4*)(o + (size_t)rr*512) = v;
    *(f32x4*)(o + (size_t)rr*512 + 4) = v;
  }
}

extern "C" void kernel_launch(void* const* d_in, const int* in_sizes, int n_in,
                              void* d_out, int out_size, void* d_ws, size_t ws_size,
                              hipStream_t stream){
  const float* x   = (const float*)d_in[0];
  const float* y   = (const float*)d_in[1];
  const float* fcw = (const float*)d_in[2];
  const float* fcb = (const float*)d_in[3];
  Ptr6 wbp, wcp;
  bool dictOrder = (in_sizes[10] == 76800);
  for (int i=0;i<6;i++){
    if (dictOrder){ wbp.p[i] = (const float*)d_in[4+2*i]; wcp.p[i] = (const float*)d_in[5+2*i]; }
    else          { wbp.p[i] = (const float*)d_in[4+i];   wcp.p[i] = (const float*)d_in[10+i]; }
  }
  const float* ow  = (const float*)d_in[16];
  const float* obp = (const float*)d_in[17];
  float* out = (float*)d_out;

  static const int CIN[6]  = {512,512,512,512,256,128};
  static const int COUT[6] = {512,512,512,256,128,64};
  static const int MPAD[6] = {1536,1536,1536,768,384,256};
  static const int LC[6]   = {9,9,9,8,7,6};
  static const long MOFF[6] = {0,1536,3072,4608,5376,5760};
  static const long COFF[6] = {0,12288,24576,36864,49152,55296};
  static const long WOFF[6] = {0,18874368,37748736,56623104,66060288,68419584};

  const size_t actBytes  = (size_t)8*68*68*512*2;   // 37,879,808
  const size_t cbufBytes = (size_t)8*64*64*512*4;   // 67,108,864
  const size_t wAllBytes = (size_t)69009408*2;      // 138,018,816
  const size_t w2OneBytes= (size_t)18874368*2;      // 37,748,736
  const size_t partBytes = (size_t)512*512*2*4;     // 2,097,152

  char* ws = (char*)d_ws; size_t off = 0;
  auto alloc = [&](size_t bytes)->void*{ void* p = ws + off; off += (bytes + 255) & ~(size_t)255; return p; };

  // probe batched-path footprint
  size_t needBatched = 0;
  {
    size_t o2 = 0;
    auto a2 = [&](size_t b){ o2 += (b + 255) & ~(size_t)255; };
    a2(actBytes); a2(actBytes); a2(cbufBytes); a2(wAllBytes);
    a2(6*8*100*4); a2((size_t)6016*128*2); a2((size_t)58368*128*2); a2(partBytes); a2(1024*4);
    needBatched = o2;
  }
  const bool batched = (ws_size >= needBatched);

  unsigned short* actA = (unsigned short*)alloc(actBytes);
  unsigned short* actB = (unsigned short*)alloc(actBytes);
  float* cbuf = (float*)alloc(cbufBytes);
  unsigned short* W2all = nullptr; unsigned short* W2one = nullptr; unsigned short* wboi = nullptr;
  if (batched){
    W2all = (unsigned short*)alloc(wAllBytes);
    wboi  = (unsigned short*)ws;               // overlay actA+actB+cbuf (142.9MB >= 138MB), dead before castx
  } else {
    W2one = (unsigned short*)alloc(w2OneBytes);
    wboi  = (unsigned short*)cbuf;             // dead before conv writes cbuf
  }
  float* wa = (float*)alloc(6*8*100*4);
  unsigned short* wbh = (unsigned short*)alloc((size_t)6016*128*2);
  unsigned short* wach = (unsigned short*)alloc((size_t)58368*128*2);
  float* partial = (float*)alloc(partBytes);
  float* bnmr = (float*)alloc(1024*4);

  wa_kernel<<<48, 128, 0, stream>>>(y, fcw, fcb, wa);
  wbh_all_kernel<<<6016*128/256, 256, 0, stream>>>(wbp, wbh);
  wach_all_kernel<<<58368*128/256, 256, 0, stream>>>(wcp, wa, wach);

  if (batched){
    LTab tab;
    tab.wbh = wbh; tab.wach = wach; tab.wboi = wboi; tab.w2 = W2all;
    int gsz[6], tsz[6];
    for (int l=0;l<6;l++){
      tab.mblk[l] = MPAD[l]/128; tab.nblk[l] = 3*CIN[l]/128;
      tab.M3[l] = 3*COUT[l]; tab.N3[l] = 3*CIN[l];
      tab.CINt[l] = CIN[l]; tab.COUTt[l] = COUT[l];
      tab.moff[l] = MOFF[l]; tab.coff[l] = COFF[l]; tab.woff[l] = WOFF[l];
      gsz[l] = tab.mblk[l]*tab.nblk[l]*8; tsz[l] = 8*COUT[l];
    }
    tab.cumg[0] = 0; tab.cumt[0] = 0;
    for (int l=0;l<6;l++){ tab.cumg[l+1] = tab.cumg[l] + gsz[l]; tab.cumt[l+1] = tab.cumt[l] + tsz[l]; }
    wgen_all_kernel<<<tab.cumg[6], 256, 0, stream>>>(tab);
    wtr_all_kernel<<<tab.cumt[6], 256, 0, stream>>>(tab);
  }

  castx_kernel<<<8*68*8, 256, 0, stream>>>(x, actA);

  unsigned short* ain = actA; unsigned short* aout = actB;
  for (int l=0;l<6;l++){
    const unsigned short* W2l;
    if (batched){
      W2l = W2all + WOFF[l];
    } else {
      int M3 = 3*COUT[l], N3 = 3*CIN[l];
      wgen_kernel<<<dim3(MPAD[l]/128, N3/128, 8), 256, 0, stream>>>(
          wbh + (size_t)MOFF[l]*128, wach + (size_t)COFF[l]*128, wboi, M3, N3);
      wtr_kernel<<<8*COUT[l], 256, 0, stream>>>(wboi, W2one, CIN[l], COUT[l]);
      W2l = W2one;
    }
    switch(l){
      case 0: case 1: case 2:
        conv_kernel<512,512><<<dim3(8,16,8),256,0,stream>>>(ain, W2l, cbuf, partial); break;
      case 3:
        conv_kernel<512,256><<<dim3(4,16,8),256,0,stream>>>(ain, W2l, cbuf, partial); break;
      case 4:
        conv_kernel<256,128><<<dim3(2,16,8),256,0,stream>>>(ain, W2l, cbuf, partial); break;
      case 5:
        conv_kernel<128,64><<<dim3(1,16,8),256,0,stream>>>(ain, W2l, cbuf, partial); break;
    }
    bnfin_kernel<<<2, 256, 0, stream>>>(partial, bnmr, COUT[l]);
    bnapply_kernel<<<8*68, 256, 0, stream>>>(cbuf, bnmr, aout, LC[l]);
    unsigned short* tmp = ain; ain = aout; aout = tmp;
  }
  convup_kernel<<<(8*4096)/256, 256, 0, stream>>>(ain, ow, obp, out);
}

// Round 10
// 1168.844 us; speedup vs baseline: 1.1810x; 1.0739x over previous
//
#include <hip/hip_runtime.h>
#include <stdint.h>

typedef __attribute__((ext_vector_type(8))) short short8;
typedef __attribute__((ext_vector_type(4))) float f32x4;
typedef __attribute__((ext_vector_type(4))) unsigned int u32x4;

struct Ptr6 { const float* p[6]; };

struct LTab {
  const unsigned short* wbh; const unsigned short* wach;
  unsigned short* wboi; unsigned short* w2;
  int cumg[7]; int cumt[7];
  int mblk[6]; int nblk[6]; int M3[6]; int N3[6]; int CINt[6]; int COUTt[6];
  long moff[6]; long coff[6]; long woff[6];
};

__device__ __forceinline__ float bf2f(unsigned short u){
  union { unsigned int i; float f; } x; x.i = ((unsigned int)u) << 16; return x.f;
}
__device__ __forceinline__ unsigned short f2bf(float f){
  union { float f; unsigned int i; } x; x.f = f;
  unsigned int r = x.i + 0x7fffu + ((x.i >> 16) & 1u);
  return (unsigned short)(r >> 16);
}

// async global->LDS, 16B per lane; LDS dest = wave-uniform base + lane*16
__device__ __forceinline__ void gll16(const void* g, void* l){
  __builtin_amdgcn_global_load_lds((const __attribute__((address_space(1))) void*)g,
                                   (__attribute__((address_space(3))) void*)l, 16, 0, 0);
}

// ---------------- hypernet: wa[l][b][k] = y[b]·fc_w[l][k] + fc_b[l][k] ----------------
__global__ void wa_kernel(const float* __restrict__ y, const float* __restrict__ fcw,
                          const float* __restrict__ fcb, float* __restrict__ wa){
  int l = blockIdx.x >> 3, b = blockIdx.x & 7;
  int k = threadIdx.x;
  if (k >= 100) return;
  const float* yr = y + b*512;
  const float* wr = fcw + (l*100 + k)*512;
  float s = 0.f;
  for (int j=0;j<512;j++) s += yr[j]*wr[j];
  wa[(l*8+b)*100 + k] = s + fcb[l*100 + k];
}

// ---------------- all layers: cast WB -> bf16, rows padded, K padded to 128 -------------
__global__ void wbh_all_kernel(Ptr6 wb, unsigned short* __restrict__ o){
  const int roff1=1536, roff2=3072, roff3=4608, roff4=5376, roff5=5760;
  int idx = blockIdx.x*256 + threadIdx.x;   // 6016*128 total
  int row = idx >> 7, k = idx & 127;
  int l, r;
  if      (row < roff1){ l=0; r=row; }
  else if (row < roff2){ l=1; r=row-roff1; }
  else if (row < roff3){ l=2; r=row-roff2; }
  else if (row < roff4){ l=3; r=row-roff3; }
  else if (row < roff5){ l=4; r=row-roff4; }
  else                 { l=5; r=row-roff5; }
  const int m3[6] = {1536,1536,1536,768,384,192};
  float v = (r < m3[l] && k < 100) ? wb.p[l][r*100 + k] : 0.f;
  o[idx] = f2bf(v);
}

// ---------------- all layers: wach[l][b][i][k] = wa[l][b][k]*WC[l][i][k], K pad 128 -----
__global__ void wach_all_kernel(Ptr6 wc, const float* __restrict__ wa,
                                unsigned short* __restrict__ o){
  const int c1=12288, c2=24576, c3=36864, c4=49152, c5=55296;
  int idx = blockIdx.x*256 + threadIdx.x;   // 58368*128 total
  int row = idx >> 7, k = idx & 127;
  int l, r, n3;
  if      (row < c1){ l=0; r=row;    n3=1536; }
  else if (row < c2){ l=1; r=row-c1; n3=1536; }
  else if (row < c3){ l=2; r=row-c2; n3=1536; }
  else if (row < c4){ l=3; r=row-c3; n3=1536; }
  else if (row < c5){ l=4; r=row-c4; n3=768; }
  else              { l=5; r=row-c5; n3=384; }
  int b = r / n3, i = r % n3;
  float v = (k < 100) ? wa[(l*8+b)*100 + k] * wc.p[l][i*100 + k] : 0.f;
  o[idx] = f2bf(v);
}

// ---------------- weight-gen GEMM body: wboi[b][o][i] = WBh[o]·wach[b][i] (K=128) -------
__device__ __forceinline__ void wgen_body(
    const unsigned short* __restrict__ wbh, const unsigned short* __restrict__ wach,
    unsigned short* __restrict__ wboi, int M3, int N3, int m0, int n0, int b,
    unsigned short* At, unsigned short* Bt){
  const int t = threadIdx.x;
  const unsigned short* As = wbh + (size_t)m0*128;
  const unsigned short* Bs = wach + ((size_t)b*N3 + n0)*128;
  #pragma unroll
  for (int j=0;j<8;j++){
    int c = j*256 + t;
    int row = c >> 4, q = c & 15;
    *(u32x4*)&At[row*136 + q*8] = *(const u32x4*)&As[row*128 + q*8];
    *(u32x4*)&Bt[row*136 + q*8] = *(const u32x4*)&Bs[row*128 + q*8];
  }
  __syncthreads();
  const int wv = t >> 6, lane = t & 63;
  const int wm = (wv >> 1)*64, wn = (wv & 1)*64;
  const int lr = lane & 15, lkg = lane >> 4, lk8 = lkg*8;
  f32x4 acc[4][4];
  #pragma unroll
  for (int i=0;i<4;i++) for (int j=0;j<4;j++) acc[i][j] = (f32x4){0,0,0,0};
  #pragma unroll
  for (int kc=0;kc<4;kc++){
    short8 a[4], bv[4];
    #pragma unroll
    for (int mi=0;mi<4;mi++) a[mi] = *(const short8*)&At[(wm+mi*16+lr)*136 + kc*32 + lk8];
    #pragma unroll
    for (int ni=0;ni<4;ni++) bv[ni] = *(const short8*)&Bt[(wn+ni*16+lr)*136 + kc*32 + lk8];
    #pragma unroll
    for (int mi=0;mi<4;mi++)
      #pragma unroll
      for (int ni=0;ni<4;ni++)
        acc[mi][ni] = __builtin_amdgcn_mfma_f32_16x16x32_bf16(a[mi], bv[ni], acc[mi][ni], 0,0,0);
  }
  #pragma unroll
  for (int mi=0;mi<4;mi++)
    #pragma unroll
    for (int ni=0;ni<4;ni++)
      #pragma unroll
      for (int r=0;r<4;r++){
        int o = m0 + wm + mi*16 + lkg*4 + r;
        int i = n0 + wn + ni*16 + lr;
        if (o < M3) wboi[((size_t)b*M3 + o)*N3 + i] = f2bf(acc[mi][ni][r]);
      }
}

__global__ __launch_bounds__(256) void wgen_all_kernel(LTab tab){
  __shared__ unsigned short At[128*136];
  __shared__ unsigned short Bt[128*136];
  int bid = blockIdx.x;
  int l = 0;
  #pragma unroll
  for (int i=1;i<6;i++) if (bid >= tab.cumg[i]) l = i;
  int rem = bid - tab.cumg[l];
  int mb = rem % tab.mblk[l];
  int r2 = rem / tab.mblk[l];
  int nb = r2 % tab.nblk[l];
  int b  = r2 / tab.nblk[l];
  wgen_body(tab.wbh + tab.moff[l]*128, tab.wach + tab.coff[l]*128,
            tab.wboi + tab.woff[l], tab.M3[l], tab.N3[l], mb*128, nb*128, b, At, Bt);
}

__global__ __launch_bounds__(256) void wgen_kernel(
    const unsigned short* __restrict__ wbh, const unsigned short* __restrict__ wach,
    unsigned short* __restrict__ wboi, int M3, int N3){
  __shared__ unsigned short At[128*136];
  __shared__ unsigned short Bt[128*136];
  wgen_body(wbh, wach, wboi, M3, N3, blockIdx.x*128, blockIdx.y*128, blockIdx.z, At, Bt);
}

// ---------------- weight transpose body: W2[b][tap][co][ci] <- wboi, 16B stores ---------
__device__ __forceinline__ void wtr_body(
    const unsigned short* __restrict__ wboi, unsigned short* __restrict__ W2,
    int CIN, int COUT, int co, int b, unsigned short* buf){
  const int t = threadIdx.x;
  const int n = 9*CIN;
  const unsigned short* src = wboi + ((size_t)b*3*COUT + 3*co)*(size_t)(3*CIN);
  for (int i = t*8; i < n; i += 2048) *(u32x4*)&buf[i] = *(const u32x4*)&src[i];
  __syncthreads();
  const int nch = n >> 3;
  const int cpr = CIN >> 3;
  for (int idx = t; idx < nch; idx += 256){
    int tap = idx / cpr, cig = idx - tap*cpr;
    short8 v;
    #pragma unroll
    for (int j=0;j<8;j++) v[j] = (short)buf[(cig*8+j)*9 + tap];
    *(short8*)&W2[(((size_t)(b*9 + tap)*COUT) + co)*CIN + cig*8] = v;
  }
}

__global__ void wtr_all_kernel(LTab tab){
  __shared__ unsigned short buf[9*512];
  int bid = blockIdx.x;
  int l = 0;
  #pragma unroll
  for (int i=1;i<6;i++) if (bid >= tab.cumt[i]) l = i;
  int rem = bid - tab.cumt[l];
  int co = rem % tab.COUTt[l];
  int b  = rem / tab.COUTt[l];
  wtr_body(tab.wboi + tab.woff[l], tab.w2 + tab.woff[l], tab.CINt[l], tab.COUTt[l], co, b, buf);
}

__global__ void wtr_kernel(const unsigned short* __restrict__ wboi, unsigned short* __restrict__ W2,
                           int CIN, int COUT){
  __shared__ unsigned short buf[9*512];
  wtr_body(wboi, W2, CIN, COUT, blockIdx.x % COUT, blockIdx.x / COUT, buf);
}

// ---------------- cast x (NCHW f32) -> padded NHWC bf16 [8][68][68][512] ----------------
__global__ void castx_kernel(const float* __restrict__ x, unsigned short* __restrict__ act){
  __shared__ float tile[64][65];
  int bid = blockIdx.x;
  int ct = bid & 7; int hp = (bid >> 3) % 68; int b = bid / 544;
  int c0 = ct * 64;
  int t = threadIdx.x;
  unsigned short* orow = act + ((size_t)(b*68 + hp)*68)*512;
  if (hp < 2 || hp >= 66){
    for (int idx = t; idx < 68*64; idx += 256){
      int wp = idx >> 6, c = idx & 63;
      orow[wp*512 + c0 + c] = 0;
    }
    return;
  }
  int h = hp - 2;
  for (int idx = t; idx < 64*64; idx += 256){
    int r = idx >> 6, w = idx & 63;
    tile[r][w] = x[((size_t)(b*512 + c0 + r)*64 + h)*64 + w];
  }
  __syncthreads();
  for (int idx = t; idx < 68*64; idx += 256){
    int wp = idx >> 6, c = idx & 63;
    float v = (wp < 2 || wp >= 66) ? 0.f : tile[c][wp-2];
    orow[wp*512 + c0 + c] = f2bf(v);
  }
}

// ---------------- conv: implicit GEMM, global_load_lds staging with pre-swizzled source -
// LDS chunk layouts (16B chunks):
//   Al slot s: tap=s>>8, q=(s>>6)&3, co=(s&63)^q   (write inverse of read swizzle co^q)
//   Pl slot s: pp=s>>2 -> (ph,pw)=pp/20,pp%20 ; q=(s&3)^((pw>>1)&3)
// Read side identical to Round 8 (conflict-free verified).
template<int CIN, int COUT>
__global__ __launch_bounds__(256, 2) void conv_kernel(
    const unsigned short* __restrict__ act, const unsigned short* __restrict__ W2,
    float* __restrict__ cbuf, float* __restrict__ partial){
  __shared__ unsigned short Al[9*256*8];    // 36864 B = 36 windows of 1024B
  __shared__ unsigned short Pl[20*20*4*8];  // 25600 B = 25 windows
  const int co0 = blockIdx.x * 64;
  const int h0 = (blockIdx.y >> 2) * 16;
  const int w0 = (blockIdx.y & 3) * 16;
  const int b = blockIdx.z;
  const int t = threadIdx.x;
  const int wv = t >> 6, lane = t & 63;
  const int lr = lane & 15, lkg = lane >> 4;

  const unsigned short* actb = act + (size_t)b*68*68*CIN;
  const unsigned short* wb = W2 + (size_t)b*9*COUT*CIN;

  // precompute per-lane staging source addresses (cs=0); advance +64B per K-step
  const unsigned short* ga[16];
  #pragma unroll
  for (int j=0;j<16;j++){
    int id = wv*16 + j;
    if (id < 36){
      int tap = id >> 2, q = id & 3;
      int co = lane ^ q;
      ga[j] = &wb[((size_t)(tap*COUT + co0 + co))*CIN + q*8];
    } else if (id < 61){
      int s = (id-36)*64 + lane;
      int pp = s >> 2;
      int ph = pp/20, pw = pp - ph*20;
      int q = (s&3) ^ ((pw>>1)&3);
      ga[j] = &actb[(size_t)((h0+ph)*68 + (w0+pw))*CIN + q*8];
    } else {
      ga[j] = nullptr;
    }
  }

  f32x4 acc[4][4];
  #pragma unroll
  for (int i=0;i<4;i++) for (int j=0;j<4;j++) acc[i][j] = (f32x4){0,0,0,0};

  for (int cs = 0; cs < CIN/32; ++cs){
    #pragma unroll
    for (int j=0;j<16;j++){
      int id = wv*16 + j;
      if (id < 61){
        unsigned short* lp = (id < 36) ? &Al[id*512] : &Pl[(id-36)*512];
        gll16((const void*)ga[j], (void*)lp);
        ga[j] += 32;   // +32 shorts = +64 B = next 32-channel chunk
      }
    }
    __syncthreads();
    #pragma unroll
    for (int kh=0;kh<3;kh++){
      #pragma unroll
      for (int kw=0;kw<3;kw++){
        const int tap = kh*3 + kw;
        short8 a[4], bv[4];
        #pragma unroll
        for (int mi=0;mi<4;mi++)
          a[mi] = *(const short8*)&Al[(tap*256 + lkg*64 + ((mi*16+lr)^lkg))*8];
        #pragma unroll
        for (int ni=0;ni<4;ni++){
          int pr = wv*4 + ni + 2*kh;
          int pc = lr + 2*kw;
          bv[ni] = *(const short8*)&Pl[((pr*20+pc)*4 + (lkg ^ ((pc>>1)&3)))*8];
        }
        #pragma unroll
        for (int mi=0;mi<4;mi++)
          #pragma unroll
          for (int ni=0;ni<4;ni++)
            acc[mi][ni] = __builtin_amdgcn_mfma_f32_16x16x32_bf16(a[mi], bv[ni], acc[mi][ni], 0,0,0);
      }
    }
    __syncthreads();
  }
  float* ob = cbuf + (size_t)b*64*64*COUT;
  #pragma unroll
  for (int mi=0;mi<4;mi++){
    int co = co0 + mi*16 + lkg*4;
    #pragma unroll
    for (int ni=0;ni<4;ni++){
      int hh = h0 + wv*4 + ni;
      int ww = w0 + lr;
      *(f32x4*)&ob[(size_t)(hh*64 + ww)*COUT + co] = acc[mi][ni];
    }
  }
  // BN partial stats: butterfly over the 16 lr lanes, deterministic per-(tile,wave) store
  float ps[4][4], pq[4][4];
  #pragma unroll
  for (int mi=0;mi<4;mi++)
    #pragma unroll
    for (int r=0;r<4;r++){ ps[mi][r]=0.f; pq[mi][r]=0.f; }
  #pragma unroll
  for (int mi=0;mi<4;mi++)
    #pragma unroll
    for (int ni=0;ni<4;ni++)
      #pragma unroll
      for (int r=0;r<4;r++){
        float v = acc[mi][ni][r];
        ps[mi][r] += v; pq[mi][r] += v*v;
      }
  #pragma unroll
  for (int m=1;m<16;m<<=1)
    #pragma unroll
    for (int mi=0;mi<4;mi++)
      #pragma unroll
      for (int r=0;r<4;r++){
        ps[mi][r] += __shfl_xor(ps[mi][r], m);
        pq[mi][r] += __shfl_xor(pq[mi][r], m);
      }
  if (lr == 0){
    // 128 spatial tiles x 4 waves = 512 deterministic slots per channel
    const int tile = (blockIdx.y*8 + blockIdx.z)*4 + wv;
    #pragma unroll
    for (int mi=0;mi<4;mi++)
      #pragma unroll
      for (int r=0;r<4;r++){
        int co = co0 + mi*16 + lkg*4 + r;
        ((float2*)partial)[co*512 + tile] = make_float2(ps[mi][r], pq[mi][r]);
      }
  }
}

// ---------------- reduce partials -> mean / rsqrt (32 lanes per channel) ----------------
__global__ void bnfin_kernel(const float* __restrict__ partial, float* __restrict__ bnmr, int C){
  int lane = threadIdx.x & 31, ch8 = threadIdx.x >> 5;
  int c = blockIdx.x*8 + ch8;
  if (c >= C) return;
  const float2* p = (const float2*)partial + (size_t)c*512;
  float s=0.f, q=0.f;
  for (int tl=lane; tl<512; tl+=32){
    float2 v = p[tl];
    s += v.x; q += v.y;
  }
  #pragma unroll
  for (int m=1;m<32;m<<=1){
    s += __shfl_xor(s, m);
    q += __shfl_xor(q, m);
  }
  if (lane == 0){
    const float inv_n = 1.f/32768.f;
    float mean = s*inv_n;
    float var = q*inv_n - mean*mean;
    bnmr[c] = mean;
    bnmr[512 + c] = rsqrtf(var + 1e-5f);
  }
}

// ---------------- BN apply + ReLU + bf16 cast into padded NHWC (writes border zeros) ----
__global__ void bnapply_kernel(const float* __restrict__ cbuf, const float* __restrict__ bnmr,
                               unsigned short* __restrict__ actout, int lc){
  const int C = 1 << lc;
  const int bid = blockIdx.x;
  const int hp = bid % 68, b = bid / 68;
  const int t = threadIdx.x;
  unsigned short* orow = actout + (((size_t)(b*68 + hp))*68 << lc);
  const bool hb = (hp < 2) || (hp >= 66);
  const int n = 68 << lc;
  for (int idx = t; idx < n; idx += 256){
    int wp = idx >> lc, c = idx & (C-1);
    float v = 0.f;
    if (!hb && wp >= 2 && wp < 66){
      float xx = cbuf[((((size_t)b*64 + (hp-2))*64 + (wp-2)) << lc) + c];
      float z = (xx - bnmr[c]) * bnmr[512 + c];
      v = z > 0.f ? z : 0.f;
    }
    orow[idx] = f2bf(v);
  }
}

// ---------------- fused 1x1 conv (64->1) + 8x nearest upsample ----------------
__global__ void convup_kernel(const unsigned short* __restrict__ act, const float* __restrict__ ow,
                              const float* __restrict__ ob, float* __restrict__ out){
  int idx = blockIdx.x*256 + threadIdx.x;   // 8*4096
  int b = idx >> 12, p = idx & 4095;
  int h = p >> 6, w = p & 63;
  const unsigned short* ar = act + (((size_t)(b*68 + h+2))*68 + (w+2))*64;
  float s = 0.f;
  #pragma unroll
  for (int c=0;c<64;c++) s += bf2f(ar[c]) * ow[c];
  s += ob[0];
  f32x4 v = {s,s,s,s};
  float* o = out + (((size_t)b*512 + h*8)*512) + w*8;
  #pragma unroll
  for (int rr=0;rr<8;rr++){
    *(f32x4*)(o + (size_t)rr*512) = v;
    *(f32x4*)(o + (size_t)rr*512 + 4) = v;
  }
}

extern "C" void kernel_launch(void* const* d_in, const int* in_sizes, int n_in,
                              void* d_out, int out_size, void* d_ws, size_t ws_size,
                              hipStream_t stream){
  const float* x   = (const float*)d_in[0];
  const float* y   = (const float*)d_in[1];
  const float* fcw = (const float*)d_in[2];
  const float* fcb = (const float*)d_in[3];
  Ptr6 wbp, wcp;
  bool dictOrder = (in_sizes[10] == 76800);
  for (int i=0;i<6;i++){
    if (dictOrder){ wbp.p[i] = (const float*)d_in[4+2*i]; wcp.p[i] = (const float*)d_in[5+2*i]; }
    else          { wbp.p[i] = (const float*)d_in[4+i];   wcp.p[i] = (const float*)d_in[10+i]; }
  }
  const float* ow  = (const float*)d_in[16];
  const float* obp = (const float*)d_in[17];
  float* out = (float*)d_out;

  static const int CIN[6]  = {512,512,512,512,256,128};
  static const int COUT[6] = {512,512,512,256,128,64};
  static const int MPAD[6] = {1536,1536,1536,768,384,256};
  static const int LC[6]   = {9,9,9,8,7,6};
  static const long MOFF[6] = {0,1536,3072,4608,5376,5760};
  static const long COFF[6] = {0,12288,24576,36864,49152,55296};
  static const long WOFF[6] = {0,18874368,37748736,56623104,66060288,68419584};

  const size_t actBytes  = (size_t)8*68*68*512*2;   // 37,879,808
  const size_t cbufBytes = (size_t)8*64*64*512*4;   // 67,108,864
  const size_t wAllBytes = (size_t)69009408*2;      // 138,018,816
  const size_t w2OneBytes= (size_t)18874368*2;      // 37,748,736
  const size_t partBytes = (size_t)512*512*2*4;     // 2,097,152

  char* ws = (char*)d_ws; size_t off = 0;
  auto alloc = [&](size_t bytes)->void*{ void* p = ws + off; off += (bytes + 255) & ~(size_t)255; return p; };

  // probe batched-path footprint
  size_t needBatched = 0;
  {
    size_t o2 = 0;
    auto a2 = [&](size_t b){ o2 += (b + 255) & ~(size_t)255; };
    a2(actBytes); a2(actBytes); a2(cbufBytes); a2(wAllBytes);
    a2(6*8*100*4); a2((size_t)6016*128*2); a2((size_t)58368*128*2); a2(partBytes); a2(1024*4);
    needBatched = o2;
  }
  const bool batched = (ws_size >= needBatched);

  unsigned short* actA = (unsigned short*)alloc(actBytes);
  unsigned short* actB = (unsigned short*)alloc(actBytes);
  float* cbuf = (float*)alloc(cbufBytes);
  unsigned short* W2all = nullptr; unsigned short* W2one = nullptr; unsigned short* wboi = nullptr;
  if (batched){
    W2all = (unsigned short*)alloc(wAllBytes);
    wboi  = (unsigned short*)ws;               // overlay actA+actB+cbuf (142.9MB >= 138MB), dead before castx
  } else {
    W2one = (unsigned short*)alloc(w2OneBytes);
    wboi  = (unsigned short*)cbuf;             // dead before conv writes cbuf
  }
  float* wa = (float*)alloc(6*8*100*4);
  unsigned short* wbh = (unsigned short*)alloc((size_t)6016*128*2);
  unsigned short* wach = (unsigned short*)alloc((size_t)58368*128*2);
  float* partial = (float*)alloc(partBytes);
  float* bnmr = (float*)alloc(1024*4);

  wa_kernel<<<48, 128, 0, stream>>>(y, fcw, fcb, wa);
  wbh_all_kernel<<<6016*128/256, 256, 0, stream>>>(wbp, wbh);
  wach_all_kernel<<<58368*128/256, 256, 0, stream>>>(wcp, wa, wach);

  if (batched){
    LTab tab;
    tab.wbh = wbh; tab.wach = wach; tab.wboi = wboi; tab.w2 = W2all;
    int gsz[6], tsz[6];
    for (int l=0;l<6;l++){
      tab.mblk[l] = MPAD[l]/128; tab.nblk[l] = 3*CIN[l]/128;
      tab.M3[l] = 3*COUT[l]; tab.N3[l] = 3*CIN[l];
      tab.CINt[l] = CIN[l]; tab.COUTt[l] = COUT[l];
      tab.moff[l] = MOFF[l]; tab.coff[l] = COFF[l]; tab.woff[l] = WOFF[l];
      gsz[l] = tab.mblk[l]*tab.nblk[l]*8; tsz[l] = 8*COUT[l];
    }
    tab.cumg[0] = 0; tab.cumt[0] = 0;
    for (int l=0;l<6;l++){ tab.cumg[l+1] = tab.cumg[l] + gsz[l]; tab.cumt[l+1] = tab.cumt[l] + tsz[l]; }
    wgen_all_kernel<<<tab.cumg[6], 256, 0, stream>>>(tab);
    wtr_all_kernel<<<tab.cumt[6], 256, 0, stream>>>(tab);
  }

  castx_kernel<<<8*68*8, 256, 0, stream>>>(x, actA);

  unsigned short* ain = actA; unsigned short* aout = actB;
  for (int l=0;l<6;l++){
    const unsigned short* W2l;
    if (batched){
      W2l = W2all + WOFF[l];
    } else {
      int M3 = 3*COUT[l], N3 = 3*CIN[l];
      wgen_kernel<<<dim3(MPAD[l]/128, N3/128, 8), 256, 0, stream>>>(
          wbh + (size_t)MOFF[l]*128, wach + (size_t)COFF[l]*128, wboi, M3, N3);
      wtr_kernel<<<8*COUT[l], 256, 0, stream>>>(wboi, W2one, CIN[l], COUT[l]);
      W2l = W2one;
    }
    switch(l){
      case 0: case 1: case 2:
        conv_kernel<512,512><<<dim3(8,16,8),256,0,stream>>>(ain, W2l, cbuf, partial); break;
      case 3:
        conv_kernel<512,256><<<dim3(4,16,8),256,0,stream>>>(ain, W2l, cbuf, partial); break;
      case 4:
        conv_kernel<256,128><<<dim3(2,16,8),256,0,stream>>>(ain, W2l, cbuf, partial); break;
      case 5:
        conv_kernel<128,64><<<dim3(1,16,8),256,0,stream>>>(ain, W2l, cbuf, partial); break;
    }
    bnfin_kernel<<<COUT[l]/8, 256, 0, stream>>>(partial, bnmr, COUT[l]);
    bnapply_kernel<<<8*68, 256, 0, stream>>>(cbuf, bnmr, aout, LC[l]);
    unsigned short* tmp = ain; ain = aout; aout = tmp;
  }
  convup_kernel<<<(8*4096)/256, 256, 0, stream>>>(ain, ow, obp, out);
}

// Round 12
// 1076.412 us; speedup vs baseline: 1.2824x; 1.0859x over previous
//
#include <hip/hip_runtime.h>
#include <stdint.h>

typedef __attribute__((ext_vector_type(8))) short short8;
typedef __attribute__((ext_vector_type(4))) float f32x4;
typedef __attribute__((ext_vector_type(4))) unsigned int u32x4;

struct Ptr6 { const float* p[6]; };

struct LTab {
  const unsigned short* wbh; const unsigned short* wach;
  unsigned short* wboi; unsigned short* w2;
  int cumg[7]; int cumt[7];
  int mblk[6]; int nblk[6]; int M3[6]; int N3[6]; int CINt[6]; int COUTt[6];
  long moff[6]; long coff[6]; long woff[6];
};

__device__ __forceinline__ float bf2f(unsigned short u){
  union { unsigned int i; float f; } x; x.i = ((unsigned int)u) << 16; return x.f;
}
__device__ __forceinline__ unsigned short f2bf(float f){
  union { float f; unsigned int i; } x; x.f = f;
  unsigned int r = x.i + 0x7fffu + ((x.i >> 16) & 1u);
  return (unsigned short)(r >> 16);
}

// async global->LDS, 16B per lane; LDS dest = wave-uniform base + lane*16
__device__ __forceinline__ void gll16(const void* g, void* l){
  __builtin_amdgcn_global_load_lds((const __attribute__((address_space(1))) void*)g,
                                   (__attribute__((address_space(3))) void*)l, 16, 0, 0);
}

// ---------------- hypernet: wa[l][b][k] = y[b]·fc_w[l][k] + fc_b[l][k] ----------------
__global__ void wa_kernel(const float* __restrict__ y, const float* __restrict__ fcw,
                          const float* __restrict__ fcb, float* __restrict__ wa){
  int l = blockIdx.x >> 3, b = blockIdx.x & 7;
  int k = threadIdx.x;
  if (k >= 100) return;
  const float* yr = y + b*512;
  const float* wr = fcw + (l*100 + k)*512;
  float s = 0.f;
  for (int j=0;j<512;j++) s += yr[j]*wr[j];
  wa[(l*8+b)*100 + k] = s + fcb[l*100 + k];
}

// ---------------- all layers: cast WB -> bf16, rows padded, K padded to 128 -------------
__global__ void wbh_all_kernel(Ptr6 wb, unsigned short* __restrict__ o){
  const int roff1=1536, roff2=3072, roff3=4608, roff4=5376, roff5=5760;
  int idx = blockIdx.x*256 + threadIdx.x;   // 6016*128 total
  int row = idx >> 7, k = idx & 127;
  int l, r;
  if      (row < roff1){ l=0; r=row; }
  else if (row < roff2){ l=1; r=row-roff1; }
  else if (row < roff3){ l=2; r=row-roff2; }
  else if (row < roff4){ l=3; r=row-roff3; }
  else if (row < roff5){ l=4; r=row-roff4; }
  else                 { l=5; r=row-roff5; }
  const int m3[6] = {1536,1536,1536,768,384,192};
  float v = (r < m3[l] && k < 100) ? wb.p[l][r*100 + k] : 0.f;
  o[idx] = f2bf(v);
}

// ---------------- all layers: wach[l][b][i][k] = wa[l][b][k]*WC[l][i][k], K pad 128 -----
__global__ void wach_all_kernel(Ptr6 wc, const float* __restrict__ wa,
                                unsigned short* __restrict__ o){
  const int c1=12288, c2=24576, c3=36864, c4=49152, c5=55296;
  int idx = blockIdx.x*256 + threadIdx.x;   // 58368*128 total
  int row = idx >> 7, k = idx & 127;
  int l, r, n3;
  if      (row < c1){ l=0; r=row;    n3=1536; }
  else if (row < c2){ l=1; r=row-c1; n3=1536; }
  else if (row < c3){ l=2; r=row-c2; n3=1536; }
  else if (row < c4){ l=3; r=row-c3; n3=1536; }
  else if (row < c5){ l=4; r=row-c4; n3=768; }
  else              { l=5; r=row-c5; n3=384; }
  int b = r / n3, i = r % n3;
  float v = (k < 100) ? wa[(l*8+b)*100 + k] * wc.p[l][i*100 + k] : 0.f;
  o[idx] = f2bf(v);
}

// ---------------- weight-gen GEMM body: wboi[b][o][i] = WBh[o]·wach[b][i] (K=128) -------
__device__ __forceinline__ void wgen_body(
    const unsigned short* __restrict__ wbh, const unsigned short* __restrict__ wach,
    unsigned short* __restrict__ wboi, int M3, int N3, int m0, int n0, int b,
    unsigned short* At, unsigned short* Bt){
  const int t = threadIdx.x;
  const unsigned short* As = wbh + (size_t)m0*128;
  const unsigned short* Bs = wach + ((size_t)b*N3 + n0)*128;
  #pragma unroll
  for (int j=0;j<8;j++){
    int c = j*256 + t;
    int row = c >> 4, q = c & 15;
    *(u32x4*)&At[row*136 + q*8] = *(const u32x4*)&As[row*128 + q*8];
    *(u32x4*)&Bt[row*136 + q*8] = *(const u32x4*)&Bs[row*128 + q*8];
  }
  __syncthreads();
  const int wv = t >> 6, lane = t & 63;
  const int wm = (wv >> 1)*64, wn = (wv & 1)*64;
  const int lr = lane & 15, lkg = lane >> 4, lk8 = lkg*8;
  f32x4 acc[4][4];
  #pragma unroll
  for (int i=0;i<4;i++) for (int j=0;j<4;j++) acc[i][j] = (f32x4){0,0,0,0};
  #pragma unroll
  for (int kc=0;kc<4;kc++){
    short8 a[4], bv[4];
    #pragma unroll
    for (int mi=0;mi<4;mi++) a[mi] = *(const short8*)&At[(wm+mi*16+lr)*136 + kc*32 + lk8];
    #pragma unroll
    for (int ni=0;ni<4;ni++) bv[ni] = *(const short8*)&Bt[(wn+ni*16+lr)*136 + kc*32 + lk8];
    #pragma unroll
    for (int mi=0;mi<4;mi++)
      #pragma unroll
      for (int ni=0;ni<4;ni++)
        acc[mi][ni] = __builtin_amdgcn_mfma_f32_16x16x32_bf16(a[mi], bv[ni], acc[mi][ni], 0,0,0);
  }
  #pragma unroll
  for (int mi=0;mi<4;mi++)
    #pragma unroll
    for (int ni=0;ni<4;ni++)
      #pragma unroll
      for (int r=0;r<4;r++){
        int o = m0 + wm + mi*16 + lkg*4 + r;
        int i = n0 + wn + ni*16 + lr;
        if (o < M3) wboi[((size_t)b*M3 + o)*N3 + i] = f2bf(acc[mi][ni][r]);
      }
}

__global__ __launch_bounds__(256) void wgen_all_kernel(LTab tab){
  __shared__ unsigned short At[128*136];
  __shared__ unsigned short Bt[128*136];
  int bid = blockIdx.x;
  int l = 0;
  #pragma unroll
  for (int i=1;i<6;i++) if (bid >= tab.cumg[i]) l = i;
  int rem = bid - tab.cumg[l];
  int mb = rem % tab.mblk[l];
  int r2 = rem / tab.mblk[l];
  int nb = r2 % tab.nblk[l];
  int b  = r2 / tab.nblk[l];
  wgen_body(tab.wbh + tab.moff[l]*128, tab.wach + tab.coff[l]*128,
            tab.wboi + tab.woff[l], tab.M3[l], tab.N3[l], mb*128, nb*128, b, At, Bt);
}

__global__ __launch_bounds__(256) void wgen_kernel(
    const unsigned short* __restrict__ wbh, const unsigned short* __restrict__ wach,
    unsigned short* __restrict__ wboi, int M3, int N3){
  __shared__ unsigned short At[128*136];
  __shared__ unsigned short Bt[128*136];
  wgen_body(wbh, wach, wboi, M3, N3, blockIdx.x*128, blockIdx.y*128, blockIdx.z, At, Bt);
}

// ---------------- weight transpose -> W3 blocked+swizzled layout -----------------------
// W3 chunk order: [b][cs][tap][q][cg] (16B chunks), cg holds data of co = cg ^ q.
// Block = (b, group of 8 co). wboi reads coalesced; W3 writes in 128B runs.
__device__ __forceinline__ void wtr3_body(
    const unsigned short* __restrict__ wboi, unsigned short* __restrict__ W3,
    int CIN, int COUT, int cog, int b, unsigned short* buf){
  const int t = threadIdx.x;
  const int n = 9*CIN;                 // shorts per co
  const int stride = 9*CIN + 8;        // padded LDS stride (bank-spread for gather)
  const int cpr = n >> 3;              // 16B chunks per co
  const int NCS = CIN >> 5;
  // load 8 co regions (each contiguous 9*CIN shorts in wboi)
  for (int idx = t; idx < 8*cpr; idx += 256){
    int co_r = idx / cpr, off = idx - co_r*cpr;
    const unsigned short* src = wboi + ((size_t)b*3*COUT + 3*(cog*8+co_r))*(size_t)(3*CIN);
    *(u32x4*)&buf[co_r*stride + off*8] = *(const u32x4*)&src[off*8];
  }
  __syncthreads();
  // gather (tap, cs, q) chunks and write swizzled-blocked
  const int total = 9*NCS*4*8;         // = 8*cpr
  for (int idx = t; idx < total; idx += 256){
    int co_in = idx & 7;
    int trip = idx >> 3;
    int q = trip & 3;
    int tcs = trip >> 2;
    int tap = tcs % 9;
    int cs  = tcs / 9;
    int ci0 = cs*32 + q*8;
    short8 v;
    #pragma unroll
    for (int e=0;e<8;e++) v[e] = (short)buf[co_in*stride + (ci0+e)*9 + tap];
    size_t dst = ((((size_t)(b*NCS + cs)*9 + tap)*4 + q)*COUT + (cog*8 + (co_in^q)))*8;
    *(short8*)&W3[dst] = v;
  }
}

__global__ void wtr_all_kernel(LTab tab){
  __shared__ unsigned short buf[8*(9*512+8)];
  int bid = blockIdx.x;
  int l = 0;
  #pragma unroll
  for (int i=1;i<6;i++) if (bid >= tab.cumt[i]) l = i;
  int rem = bid - tab.cumt[l];
  int ng = tab.COUTt[l] >> 3;
  int cog = rem % ng;
  int b  = rem / ng;
  wtr3_body(tab.wboi + tab.woff[l], tab.w2 + tab.woff[l], tab.CINt[l], tab.COUTt[l], cog, b, buf);
}

__global__ void wtr_kernel(const unsigned short* __restrict__ wboi, unsigned short* __restrict__ W3,
                           int CIN, int COUT){
  __shared__ unsigned short buf[8*(9*512+8)];
  int ng = COUT >> 3;
  wtr3_body(wboi, W3, CIN, COUT, blockIdx.x % ng, blockIdx.x / ng, buf);
}

// ---------------- cast x (NCHW f32) -> padded NHWC bf16 [8][68][68][512] ----------------
__global__ void castx_kernel(const float* __restrict__ x, unsigned short* __restrict__ act){
  __shared__ float tile[64][65];
  int bid = blockIdx.x;
  int ct = bid & 7; int hp = (bid >> 3) % 68; int b = bid / 544;
  int c0 = ct * 64;
  int t = threadIdx.x;
  unsigned short* orow = act + ((size_t)(b*68 + hp)*68)*512;
  if (hp < 2 || hp >= 66){
    for (int idx = t; idx < 68*64; idx += 256){
      int wp = idx >> 6, c = idx & 63;
      orow[wp*512 + c0 + c] = 0;
    }
    return;
  }
  int h = hp - 2;
  for (int idx = t; idx < 64*64; idx += 256){
    int r = idx >> 6, w = idx & 63;
    tile[r][w] = x[((size_t)(b*512 + c0 + r)*64 + h)*64 + w];
  }
  __syncthreads();
  for (int idx = t; idx < 68*64; idx += 256){
    int wp = idx >> 6, c = idx & 63;
    float v = (wp < 2 || wp >= 66) ? 0.f : tile[c][wp-2];
    orow[wp*512 + c0 + c] = f2bf(v);
  }
}

// ---------------- conv: implicit GEMM, gll staging; A windows contiguous via W3 ---------
// LDS chunk layouts (16B chunks), identical to Round 8/10:
//   Al slot s: tap=s>>8, q=(s>>6)&3, slot c holds co = c^q
//   Pl slot s: pp=s>>2 -> (ph,pw) ; content q = (s&3)^((pw>>1)&3)
template<int CIN, int COUT>
__global__ __launch_bounds__(256, 2) void conv_kernel(
    const unsigned short* __restrict__ act, const unsigned short* __restrict__ W3,
    float* __restrict__ cbuf, float* __restrict__ partial){
  __shared__ unsigned short Al[9*256*8];    // 36864 B = 36 windows of 1024B
  __shared__ unsigned short Pl[20*20*4*8];  // 25600 B = 25 windows
  const int co0 = blockIdx.x * 64;
  const int h0 = (blockIdx.y >> 2) * 16;
  const int w0 = (blockIdx.y & 3) * 16;
  const int b = blockIdx.z;
  const int t = threadIdx.x;
  const int wv = t >> 6, lane = t & 63;
  const int lr = lane & 15, lkg = lane >> 4;

  const unsigned short* actb = act + (size_t)b*68*68*CIN;
  const unsigned short* w3b = W3 + (size_t)b*9*COUT*CIN;  // per-b block of W3

  // per-lane staging source addresses (cs=0)
  const unsigned short* ga[16];
  #pragma unroll
  for (int j=0;j<16;j++){
    int id = wv*16 + j;
    if (id < 36){
      int tap = id >> 2, q = id & 3;
      // W3 window: contiguous 1KB, lane-linear
      ga[j] = &w3b[((((size_t)tap)*4 + q)*COUT + co0 + lane)*8];
    } else if (id < 61){
      int s = (id-36)*64 + lane;
      int pp = s >> 2;
      int ph = pp/20, pw = pp - ph*20;
      int q = (s&3) ^ ((pw>>1)&3);
      ga[j] = &actb[(size_t)((h0+ph)*68 + (w0+pw))*CIN + q*8];
    } else {
      ga[j] = nullptr;
    }
  }

  f32x4 acc[4][4];
  #pragma unroll
  for (int i=0;i<4;i++) for (int j=0;j<4;j++) acc[i][j] = (f32x4){0,0,0,0};

  const size_t aStep = (size_t)288*COUT;   // 9*4*COUT*8 shorts per cs
  for (int cs = 0; cs < CIN/32; ++cs){
    #pragma unroll
    for (int j=0;j<16;j++){
      int id = wv*16 + j;
      if (id < 61){
        unsigned short* lp = (id < 36) ? &Al[id*512] : &Pl[(id-36)*512];
        gll16((const void*)ga[j], (void*)lp);
        ga[j] += (id < 36) ? aStep : 32;
      }
    }
    __syncthreads();
    #pragma unroll
    for (int kh=0;kh<3;kh++){
      #pragma unroll
      for (int kw=0;kw<3;kw++){
        const int tap = kh*3 + kw;
        short8 a[4], bv[4];
        #pragma unroll
        for (int mi=0;mi<4;mi++)
          a[mi] = *(const short8*)&Al[(tap*256 + lkg*64 + ((mi*16+lr)^lkg))*8];
        #pragma unroll
        for (int ni=0;ni<4;ni++){
          int pr = wv*4 + ni + 2*kh;
          int pc = lr + 2*kw;
          bv[ni] = *(const short8*)&Pl[((pr*20+pc)*4 + (lkg ^ ((pc>>1)&3)))*8];
        }
        #pragma unroll
        for (int mi=0;mi<4;mi++)
          #pragma unroll
          for (int ni=0;ni<4;ni++)
            acc[mi][ni] = __builtin_amdgcn_mfma_f32_16x16x32_bf16(a[mi], bv[ni], acc[mi][ni], 0,0,0);
      }
    }
    __syncthreads();
  }
  float* ob = cbuf + (size_t)b*64*64*COUT;
  #pragma unroll
  for (int mi=0;mi<4;mi++){
    int co = co0 + mi*16 + lkg*4;
    #pragma unroll
    for (int ni=0;ni<4;ni++){
      int hh = h0 + wv*4 + ni;
      int ww = w0 + lr;
      *(f32x4*)&ob[(size_t)(hh*64 + ww)*COUT + co] = acc[mi][ni];
    }
  }
  // BN partial stats: butterfly over the 16 lr lanes, deterministic per-(tile,wave) store
  float ps[4][4], pq[4][4];
  #pragma unroll
  for (int mi=0;mi<4;mi++)
    #pragma unroll
    for (int r=0;r<4;r++){ ps[mi][r]=0.f; pq[mi][r]=0.f; }
  #pragma unroll
  for (int mi=0;mi<4;mi++)
    #pragma unroll
    for (int ni=0;ni<4;ni++)
      #pragma unroll
      for (int r=0;r<4;r++){
        float v = acc[mi][ni][r];
        ps[mi][r] += v; pq[mi][r] += v*v;
      }
  #pragma unroll
  for (int m=1;m<16;m<<=1)
    #pragma unroll
    for (int mi=0;mi<4;mi++)
      #pragma unroll
      for (int r=0;r<4;r++){
        ps[mi][r] += __shfl_xor(ps[mi][r], m);
        pq[mi][r] += __shfl_xor(pq[mi][r], m);
      }
  if (lr == 0){
    const int tile = (blockIdx.y*8 + blockIdx.z)*4 + wv;   // 512 slots per channel
    #pragma unroll
    for (int mi=0;mi<4;mi++)
      #pragma unroll
      for (int r=0;r<4;r++){
        int co = co0 + mi*16 + lkg*4 + r;
        ((float2*)partial)[co*512 + tile] = make_float2(ps[mi][r], pq[mi][r]);
      }
  }
}

// ---------------- reduce partials -> mean / rsqrt (32 lanes per channel) ----------------
__global__ void bnfin_kernel(const float* __restrict__ partial, float* __restrict__ bnmr, int C){
  int lane = threadIdx.x & 31, ch8 = threadIdx.x >> 5;
  int c = blockIdx.x*8 + ch8;
  if (c >= C) return;
  const float2* p = (const float2*)partial + (size_t)c*512;
  float s=0.f, q=0.f;
  for (int tl=lane; tl<512; tl+=32){
    float2 v = p[tl];
    s += v.x; q += v.y;
  }
  #pragma unroll
  for (int m=1;m<32;m<<=1){
    s += __shfl_xor(s, m);
    q += __shfl_xor(q, m);
  }
  if (lane == 0){
    const float inv_n = 1.f/32768.f;
    float mean = s*inv_n;
    float var = q*inv_n - mean*mean;
    bnmr[c] = mean;
    bnmr[512 + c] = rsqrtf(var + 1e-5f);
  }
}

// ---------------- BN apply + ReLU + bf16 cast into padded NHWC (writes border zeros) ----
__global__ void bnapply_kernel(const float* __restrict__ cbuf, const float* __restrict__ bnmr,
                               unsigned short* __restrict__ actout, int lc){
  const int C = 1 << lc;
  const int bid = blockIdx.x;
  const int hp = bid % 68, b = bid / 68;
  const int t = threadIdx.x;
  unsigned short* orow = actout + (((size_t)(b*68 + hp))*68 << lc);
  const bool hb = (hp < 2) || (hp >= 66);
  const int n = 68 << lc;
  for (int idx = t; idx < n; idx += 256){
    int wp = idx >> lc, c = idx & (C-1);
    float v = 0.f;
    if (!hb && wp >= 2 && wp < 66){
      float xx = cbuf[((((size_t)b*64 + (hp-2))*64 + (wp-2)) << lc) + c];
      float z = (xx - bnmr[c]) * bnmr[512 + c];
      v = z > 0.f ? z : 0.f;
    }
    orow[idx] = f2bf(v);
  }
}

// ---------------- fused 1x1 conv (64->1) + 8x nearest upsample ----------------
__global__ void convup_kernel(const unsigned short* __restrict__ act, const float* __restrict__ ow,
                              const float* __restrict__ ob, float* __restrict__ out){
  int idx = blockIdx.x*256 + threadIdx.x;   // 8*4096
  int b = idx >> 12, p = idx & 4095;
  int h = p >> 6, w = p & 63;
  const unsigned short* ar = act + (((size_t)(b*68 + h+2))*68 + (w+2))*64;
  float s = 0.f;
  #pragma unroll
  for (int c=0;c<64;c++) s += bf2f(ar[c]) * ow[c];
  s += ob[0];
  f32x4 v = {s,s,s,s};
  float* o = out + (((size_t)b*512 + h*8)*512) + w*8;
  #pragma unroll
  for (int rr=0;rr<8;rr++){
    *(f32x4*)(o + (size_t)rr*512) = v;
    *(f32x4*)(o + (size_t)rr*512 + 4) = v;
  }
}

extern "C" void kernel_launch(void* const* d_in, const int* in_sizes, int n_in,
                              void* d_out, int out_size, void* d_ws, size_t ws_size,
                              hipStream_t stream){
  const float* x   = (const float*)d_in[0];
  const float* y   = (const float*)d_in[1];
  const float* fcw = (const float*)d_in[2];
  const float* fcb = (const float*)d_in[3];
  Ptr6 wbp, wcp;
  bool dictOrder = (in_sizes[10] == 76800);
  for (int i=0;i<6;i++){
    if (dictOrder){ wbp.p[i] = (const float*)d_in[4+2*i]; wcp.p[i] = (const float*)d_in[5+2*i]; }
    else          { wbp.p[i] = (const float*)d_in[4+i];   wcp.p[i] = (const float*)d_in[10+i]; }
  }
  const float* ow  = (const float*)d_in[16];
  const float* obp = (const float*)d_in[17];
  float* out = (float*)d_out;

  static const int CIN[6]  = {512,512,512,512,256,128};
  static const int COUT[6] = {512,512,512,256,128,64};
  static const int MPAD[6] = {1536,1536,1536,768,384,256};
  static const int LC[6]   = {9,9,9,8,7,6};
  static const long MOFF[6] = {0,1536,3072,4608,5376,5760};
  static const long COFF[6] = {0,12288,24576,36864,49152,55296};
  static const long WOFF[6] = {0,18874368,37748736,56623104,66060288,68419584};

  const size_t actBytes  = (size_t)8*68*68*512*2;   // 37,879,808
  const size_t cbufBytes = (size_t)8*64*64*512*4;   // 67,108,864
  const size_t wAllBytes = (size_t)69009408*2;      // 138,018,816
  const size_t w2OneBytes= (size_t)18874368*2;      // 37,748,736
  const size_t partBytes = (size_t)512*512*2*4;     // 2,097,152

  char* ws = (char*)d_ws; size_t off = 0;
  auto alloc = [&](size_t bytes)->void*{ void* p = ws + off; off += (bytes + 255) & ~(size_t)255; return p; };

  // probe batched-path footprint
  size_t needBatched = 0;
  {
    size_t o2 = 0;
    auto a2 = [&](size_t b){ o2 += (b + 255) & ~(size_t)255; };
    a2(actBytes); a2(actBytes); a2(cbufBytes); a2(wAllBytes);
    a2(6*8*100*4); a2((size_t)6016*128*2); a2((size_t)58368*128*2); a2(partBytes); a2(1024*4);
    needBatched = o2;
  }
  const bool batched = (ws_size >= needBatched);

  unsigned short* actA = (unsigned short*)alloc(actBytes);
  unsigned short* actB = (unsigned short*)alloc(actBytes);
  float* cbuf = (float*)alloc(cbufBytes);
  unsigned short* W3all = nullptr; unsigned short* W3one = nullptr; unsigned short* wboi = nullptr;
  if (batched){
    W3all = (unsigned short*)alloc(wAllBytes);
    wboi  = (unsigned short*)ws;               // overlay actA+actB+cbuf (142.9MB >= 138MB), dead before castx
  } else {
    W3one = (unsigned short*)alloc(w2OneBytes);
    wboi  = (unsigned short*)cbuf;             // dead before conv writes cbuf
  }
  float* wa = (float*)alloc(6*8*100*4);
  unsigned short* wbh = (unsigned short*)alloc((size_t)6016*128*2);
  unsigned short* wach = (unsigned short*)alloc((size_t)58368*128*2);
  float* partial = (float*)alloc(partBytes);
  float* bnmr = (float*)alloc(1024*4);

  wa_kernel<<<48, 128, 0, stream>>>(y, fcw, fcb, wa);
  wbh_all_kernel<<<6016*128/256, 256, 0, stream>>>(wbp, wbh);
  wach_all_kernel<<<58368*128/256, 256, 0, stream>>>(wcp, wa, wach);

  if (batched){
    LTab tab;
    tab.wbh = wbh; tab.wach = wach; tab.wboi = wboi; tab.w2 = W3all;
    int gsz[6], tsz[6];
    for (int l=0;l<6;l++){
      tab.mblk[l] = MPAD[l]/128; tab.nblk[l] = 3*CIN[l]/128;
      tab.M3[l] = 3*COUT[l]; tab.N3[l] = 3*CIN[l];
      tab.CINt[l] = CIN[l]; tab.COUTt[l] = COUT[l];
      tab.moff[l] = MOFF[l]; tab.coff[l] = COFF[l]; tab.woff[l] = WOFF[l];
      gsz[l] = tab.mblk[l]*tab.nblk[l]*8;
      tsz[l] = COUT[l];                       // 8 b x COUT/8 groups
    }
    tab.cumg[0] = 0; tab.cumt[0] = 0;
    for (int l=0;l<6;l++){ tab.cumg[l+1] = tab.cumg[l] + gsz[l]; tab.cumt[l+1] = tab.cumt[l] + tsz[l]; }
    wgen_all_kernel<<<tab.cumg[6], 256, 0, stream>>>(tab);
    wtr_all_kernel<<<tab.cumt[6], 256, 0, stream>>>(tab);
  }

  castx_kernel<<<8*68*8, 256, 0, stream>>>(x, actA);

  unsigned short* ain = actA; unsigned short* aout = actB;
  for (int l=0;l<6;l++){
    const unsigned short* W3l;
    if (batched){
      W3l = W3all + WOFF[l];
    } else {
      int M3 = 3*COUT[l], N3 = 3*CIN[l];
      wgen_kernel<<<dim3(MPAD[l]/128, N3/128, 8), 256, 0, stream>>>(
          wbh + (size_t)MOFF[l]*128, wach + (size_t)COFF[l]*128, wboi, M3, N3);
      wtr_kernel<<<COUT[l], 256, 0, stream>>>(wboi, W3one, CIN[l], COUT[l]);
      W3l = W3one;
    }
    switch(l){
      case 0: case 1: case 2:
        conv_kernel<512,512><<<dim3(8,16,8),256,0,stream>>>(ain, W3l, cbuf, partial); break;
      case 3:
        conv_kernel<512,256><<<dim3(4,16,8),256,0,stream>>>(ain, W3l, cbuf, partial); break;
      case 4:
        conv_kernel<256,128><<<dim3(2,16,8),256,0,stream>>>(ain, W3l, cbuf, partial); break;
      case 5:
        conv_kernel<128,64><<<dim3(1,16,8),256,0,stream>>>(ain, W3l, cbuf, partial); break;
    }
    bnfin_kernel<<<COUT[l]/8, 256, 0, stream>>>(partial, bnmr, COUT[l]);
    bnapply_kernel<<<8*68, 256, 0, stream>>>(cbuf, bnmr, aout, LC[l]);
    unsigned short* tmp = ain; ain = aout; aout = tmp;
  }
  convup_kernel<<<(8*4096)/256, 256, 0, stream>>>(ain, ow, obp, out);
}